// Round 4
// baseline (142.956 us; speedup 1.0000x reference)
//
#include <hip/hip_runtime.h>

// x (8,320,320) f32, u (8,12,320,320,2) f32 -> out (8,12,320,320) f32.
//
// R4: eliminate LDS staging (it re-read x 23x over: 76.8MB of the ~195MB
// kernel traffic; nt-hints were neutral in R3). Instead: (1) pad_kernel
// copies x into a 384x384 zero-ringed workspace image (4.7MB, L2-resident);
// (2) gather kernel samples the 4 bilinear corners straight from the padded
// image via one base address + immediate offsets. The 32px zero ring plus
// clamp-to-[0,PN-2] is EXACT for any integer sample coord (fully-OOB samples
// read zero ring => 0), so there is no valid-mask logic and no rare path.
// Mandatory HBM traffic: u 78.6MB + out 39.3MB + x ~8MB => ~20us floor.
#define PP 8
#define FF 12
#define MM 320
#define NN 320
#define PAD 32
#define PM (MM + 2 * PAD)        // 384
#define PN (NN + 2 * PAD)        // 384

typedef float fvec4 __attribute__((ext_vector_type(4)));
typedef float fvec2 __attribute__((ext_vector_type(2)));

__global__ __launch_bounds__(256) void pad_kernel(const float* __restrict__ x,
                                                  float* __restrict__ xp)
{
    // One vec4 per thread over 8 padded 384x384 images.
    int lin = blockIdx.x * 256 + (int)threadIdx.x;   // 0 .. 294911
    int p   = lin / (PM * PN / 4);
    int rem = lin - p * (PM * PN / 4);
    int r   = rem / (PN / 4);
    int c   = (rem - r * (PN / 4)) * 4;
    int sr  = r - PAD;
    int sc  = c - PAD;                // aligned 4-group: fully in or fully out
    fvec4 v = {0.f, 0.f, 0.f, 0.f};
    if ((unsigned)sr < MM && (unsigned)sc < NN)
        v = *(const fvec4*)(x + (size_t)p * (MM * NN) + sr * NN + sc);
    *(fvec4*)(xp + (size_t)p * (PM * PN) + r * PN + c) = v;
}

__global__ __launch_bounds__(320) void warp_gather_kernel(
    const float* __restrict__ xp,
    const float* __restrict__ u,
    float* __restrict__ out)
{
    int j  = (int)threadIdx.x;        // 0..319: lane owns one column
    int i0 = blockIdx.x * 4;          // 4 rows per block
    int pf = blockIdx.y;              // 0..95 (p*FF + f)
    int p  = pf / FF;                 // uniform -> scalar

    const float* __restrict__ img = xp  + (size_t)p  * (PM * PN);
    const float* __restrict__ ub  = u   + (size_t)pf * (MM * NN * 2);
    float* __restrict__ ob        = out + (size_t)pf * (MM * NN);

    float fj = (float)j;
#pragma unroll
    for (int r = 0; r < 4; ++r) {
        int i = i0 + r;
        // 8B coalesced flow load (dx, dy); streamed once -> nontemporal.
        fvec2 uv = __builtin_nontemporal_load(
            (const fvec2*)(ub + 2 * ((size_t)i * NN + j)));
        float sx = fj + uv.x;
        float sy = (float)i + uv.y;
        float fx0 = floorf(sx);
        float fy0 = floorf(sy);
        float wx = sx - fx0;
        float wy = sy - fy0;
        int xq = (int)fx0 + PAD;
        int yq = (int)fy0 + PAD;
        // Clamp into padded frame; zero ring makes all OOB cases exact.
        xq = min(max(xq, 0), PN - 2);
        yq = min(max(yq, 0), PM - 2);
        const float* c00 = img + yq * PN + xq;
        float v00 = c00[0];           // one base addr, imm offsets 0/4/1536/1540
        float v01 = c00[1];
        float v10 = c00[PN];
        float v11 = c00[PN + 1];
        float vt = fmaf(wx, v01 - v00, v00);
        float vb = fmaf(wx, v11 - v10, v10);
        float res = fmaf(wy, vb - vt, vt);
        __builtin_nontemporal_store(res, ob + (size_t)i * NN + j);
    }
}

extern "C" void kernel_launch(void* const* d_in, const int* in_sizes, int n_in,
                              void* d_out, int out_size, void* d_ws, size_t ws_size,
                              hipStream_t stream) {
    const float* x = (const float*)d_in[0];
    const float* u = (const float*)d_in[1];
    float* out = (float*)d_out;
    float* xp  = (float*)d_ws;        // needs 8*384*384*4 = 4,718,592 B

    dim3 pgrid((PP * PM * PN / 4) / 256);          // 1152 blocks
    pad_kernel<<<pgrid, dim3(256), 0, stream>>>(x, xp);

    dim3 ggrid(MM / 4, PP * FF);                   // 80 x 96 = 7680 blocks
    warp_gather_kernel<<<ggrid, dim3(320), 0, stream>>>(xp, u, out);
}